// Round 10
// baseline (200.972 us; speedup 1.0000x reference)
//
#include <hip/hip_runtime.h>
#include <hip/hip_bf16.h>

typedef __attribute__((ext_vector_type(8))) short bf16x8;
typedef __attribute__((ext_vector_type(4))) float f32x4;

// ---------------------------------------------------------------------------
// bf16 helpers (manual RNE pack / shift unpack)
// ---------------------------------------------------------------------------
static __device__ __forceinline__ unsigned short f2bf(float f) {
    unsigned u = __float_as_uint(f);
    unsigned r = (u + 0x7FFFu + ((u >> 16) & 1u)) >> 16;   // round-nearest-even
    return (unsigned short)r;
}
static __device__ __forceinline__ float bfLo(unsigned d) { return __uint_as_float(d << 16); }
static __device__ __forceinline__ float bfHi(unsigned d) { return __uint_as_float(d & 0xFFFF0000u); }

#define PART_BLOCKS 128
#define PART_TPB 1024             // 16 waves/block for latency hiding
#define BUCKET 32
#define CAP_SHIFT 11              // 2048 records per bucket region
#define CAP (1u << CAP_SHIFT)
#define CHUNK 2048

// ---------------------------------------------------------------------------
// MFMA GEMM: support[N,128](bf16) = A[N,128](fp32) @ W[128,128](fp32).
// Block = 128 rows, 4 waves; wave owns 32 rows x 128 cols.
// W staged fp32 in LDS [k][c]; each wave prebuilds all 32 B-frags (bf16) in
// registers; A-frags loaded directly from global (16x128B segments/inst).
// mfma_f32_16x16x32_bf16: A row=lane&15,k=(lane>>4)*8+i; B col=lane&15, same k;
// D col=lane&15, row=(lane>>4)*4+reg  [verified by round-9 pass].
// ---------------------------------------------------------------------------
__global__ __launch_bounds__(256, 2) void mfma_gemm_kernel(const float* __restrict__ A,
                                                           const float* __restrict__ W,
                                                           unsigned short* __restrict__ S,
                                                           int N) {
    __shared__ float sW[128 * 128];   // 64 KB, [k][c]
    const int t = threadIdx.x;
    const int w = t >> 6;             // wave 0..3
    const int l = t & 63;
    const int l15 = l & 15;
    const int lq = l >> 4;            // 0..3
    const int row0 = blockIdx.x * 128;

    for (int i = t * 4; i < 128 * 128; i += 256 * 4)
        *(float4*)&sW[i] = *(const float4*)&W[i];
    __syncthreads();

    bf16x8 bfrag[8][4];
#pragma unroll
    for (int tc = 0; tc < 8; ++tc) {
#pragma unroll
        for (int ks = 0; ks < 4; ++ks) {
            const int c = tc * 16 + l15;
            const int k0 = ks * 32 + lq * 8;
            bf16x8 f;
#pragma unroll
            for (int i = 0; i < 8; ++i)
                f[i] = (short)f2bf(sW[(k0 + i) * 128 + c]);
            bfrag[tc][ks] = f;
        }
    }

    f32x4 acc[2][8];
#pragma unroll
    for (int rt = 0; rt < 2; ++rt)
#pragma unroll
        for (int tc = 0; tc < 8; ++tc)
            acc[rt][tc] = (f32x4){0.f, 0.f, 0.f, 0.f};

    const int wrow = row0 + w * 32;
#pragma unroll
    for (int ks = 0; ks < 4; ++ks) {
        bf16x8 afrag[2];
#pragma unroll
        for (int rt = 0; rt < 2; ++rt) {
            const int r = wrow + rt * 16 + l15;
            bf16x8 f = (bf16x8){0, 0, 0, 0, 0, 0, 0, 0};
            if (r < N) {
                const float* p = &A[(size_t)r * 128 + ks * 32 + lq * 8];
                float4 v0 = *(const float4*)p;
                float4 v1 = *(const float4*)(p + 4);
                f[0] = (short)f2bf(v0.x); f[1] = (short)f2bf(v0.y);
                f[2] = (short)f2bf(v0.z); f[3] = (short)f2bf(v0.w);
                f[4] = (short)f2bf(v1.x); f[5] = (short)f2bf(v1.y);
                f[6] = (short)f2bf(v1.z); f[7] = (short)f2bf(v1.w);
            }
            afrag[rt] = f;
        }
#pragma unroll
        for (int rt = 0; rt < 2; ++rt)
#pragma unroll
            for (int tc = 0; tc < 8; ++tc)
                acc[rt][tc] = __builtin_amdgcn_mfma_f32_16x16x32_bf16(
                    afrag[rt], bfrag[tc][ks], acc[rt][tc], 0, 0, 0);
    }

#pragma unroll
    for (int rt = 0; rt < 2; ++rt) {
#pragma unroll
        for (int j = 0; j < 4; ++j) {
            const int r = wrow + rt * 16 + lq * 4 + j;
            if (r < N) {
                unsigned short* Sp = S + (size_t)r * 128;
#pragma unroll
                for (int tc = 0; tc < 8; ++tc)
                    Sp[tc * 16 + l15] = f2bf(acc[rt][tc][j]);
            }
        }
    }
}

// ---------------------------------------------------------------------------
// Edge-based partition into fixed-capacity bucket regions (cursor[b] = count).
// Per edge e: r=ei[e], c=ei[e+E], rr=rel[e]; emit record (dst=r,src=c) and
// (dst=c,src=r). Each ei/rel entry read ONCE (vs twice message-based).
// Record: src (17b) | rel (8b, <<17) | dstLocal (5b, <<25).
// ---------------------------------------------------------------------------
__global__ __launch_bounds__(PART_TPB) void partition_kernel(
        const int* __restrict__ ei, const int* __restrict__ rel,
        unsigned* __restrict__ cursor, unsigned* __restrict__ rec,
        int E, int nbuck, long long chunk) {
    extern __shared__ unsigned sh[];
    unsigned* hist = sh;
    unsigned* base = sh + nbuck;
    const long long start = (long long)blockIdx.x * chunk;
    long long end = start + chunk; if (end > E) end = E;
    const int t = threadIdx.x;

    for (int i = t; i < nbuck; i += PART_TPB) hist[i] = 0u;
    __syncthreads();
    for (long long e = start + t; e < end; e += PART_TPB) {
        unsigned r = (unsigned)ei[e];
        unsigned c = (unsigned)ei[e + E];
        atomicAdd(&hist[r >> 5], 1u);
        atomicAdd(&hist[c >> 5], 1u);
    }
    __syncthreads();
    for (int i = t; i < nbuck; i += PART_TPB) {
        unsigned cn = hist[i];
        base[i] = cn ? atomicAdd(&cursor[i], cn) : 0u;   // reserve range in bucket
        hist[i] = 0u;                                     // reuse as running cursor
    }
    __syncthreads();
    for (long long e = start + t; e < end; e += PART_TPB) {
        unsigned r = (unsigned)ei[e];
        unsigned c = (unsigned)ei[e + E];
        unsigned rr = (unsigned)rel[e];
        // record for dst=r (src=c)
        unsigned b1 = r >> 5;
        unsigned l1 = atomicAdd(&hist[b1], 1u);
        unsigned p1 = base[b1] + l1;
        if (p1 < CAP)
            rec[((size_t)b1 << CAP_SHIFT) + p1] = c | (rr << 17) | ((r & 31u) << 25);
        // record for dst=c (src=r)
        unsigned b2 = c >> 5;
        unsigned l2 = atomicAdd(&hist[b2], 1u);
        unsigned p2 = base[b2] + l2;
        if (p2 < CAP)
            rec[((size_t)b2 << CAP_SHIFT) + p2] = r | (rr << 17) | ((c & 31u) << 25);
    }
}

// ---------------------------------------------------------------------------
// Gather: block = 32-node bucket. Per CHUNK: stage records to registers
// (coalesced), LDS counting-sort by dstLocal, then each half-wave accumulates
// its 4 nodes' contiguous records into float4 registers, unroll-8 body.
// Single coalesced out-write, bias folded.
// ---------------------------------------------------------------------------
static __device__ __forceinline__ void accum_run(const unsigned short* __restrict__ support,
                                                 const unsigned* sorted,
                                                 const float* aLds,
                                                 unsigned s0, unsigned cq, int lane,
                                                 float4& acc) {
    unsigned j = 0;
    for (; j + 8 <= cq; j += 8) {
        unsigned rr[8]; uint2 qq[8]; float aa[8];
#pragma unroll
        for (int u = 0; u < 8; ++u) rr[u] = sorted[s0 + j + u];
#pragma unroll
        for (int u = 0; u < 8; ++u)
            qq[u] = ((const uint2*)(support + (size_t)(rr[u] & 0x1FFFFu) * 128))[lane];
#pragma unroll
        for (int u = 0; u < 8; ++u) aa[u] = aLds[(rr[u] >> 17) & 0xFFu];
#pragma unroll
        for (int u = 0; u < 8; ++u) {
            acc.x += aa[u] * bfLo(qq[u].x);
            acc.y += aa[u] * bfHi(qq[u].x);
            acc.z += aa[u] * bfLo(qq[u].y);
            acc.w += aa[u] * bfHi(qq[u].y);
        }
    }
    for (; j < cq; ++j) {
        unsigned r0 = sorted[s0 + j];
        uint2 q0 = ((const uint2*)(support + (size_t)(r0 & 0x1FFFFu) * 128))[lane];
        float a0 = aLds[(r0 >> 17) & 0xFFu];
        acc.x += a0 * bfLo(q0.x); acc.y += a0 * bfHi(q0.x);
        acc.z += a0 * bfLo(q0.y); acc.w += a0 * bfHi(q0.y);
    }
}

__global__ __launch_bounds__(256) void gather_bucket_kernel(const unsigned short* __restrict__ support,
                                                            const unsigned* __restrict__ rec,
                                                            const unsigned* __restrict__ cnt,
                                                            const float* __restrict__ alpha,
                                                            const float* __restrict__ bias,
                                                            float* __restrict__ out,
                                                            int N, int nAlpha) {
    __shared__ float aLds[256];
    __shared__ unsigned sorted[CHUNK];
    __shared__ unsigned scnt[BUCKET], sstart[BUCKET], scur[BUCKET];

    const int t = threadIdx.x;
    const int b = blockIdx.x;
    const int lane = t & 31;
    const int hw = t >> 5;            // 8 half-waves

    {   // stage alpha; row 0 (padding) forced to zero
        float a = 0.f;
        if (t > 0 && t < nAlpha) a = alpha[t];
        aLds[t] = a;
    }
    const float4 b4 = *(const float4*)&bias[lane * 4];

    float4 acc0 = make_float4(0.f, 0.f, 0.f, 0.f);
    float4 acc1 = make_float4(0.f, 0.f, 0.f, 0.f);
    float4 acc2 = make_float4(0.f, 0.f, 0.f, 0.f);
    float4 acc3 = make_float4(0.f, 0.f, 0.f, 0.f);

    const unsigned start = (unsigned)b << CAP_SHIFT;
    unsigned total = cnt[b];
    if (total > CAP) total = CAP;

    for (unsigned cb = 0; cb < total; cb += CHUNK) {
        const unsigned cc = min((unsigned)CHUNK, total - cb);
        __syncthreads();                       // protect prev chunk's LDS
        if (t < BUCKET) scnt[t] = 0u;
        __syncthreads();

        // stage 8 records/thread (coalesced) + LDS histogram
        unsigned r[8];
#pragma unroll
        for (int k = 0; k < 8; ++k) {
            unsigned i = (unsigned)(k * 256 + t);
            r[k] = 0xFFFFFFFFu;                // sentinel (valid recs < 2^30)
            if (i < cc) {
                r[k] = rec[start + cb + i];
                atomicAdd(&scnt[r[k] >> 25], 1u);
            }
        }
        __syncthreads();

        // exclusive scan of 32 counters (shfl, lanes 0-31 of wave 0)
        if (t < BUCKET) {
            unsigned c = scnt[t];
            unsigned x = c;
#pragma unroll
            for (int d = 1; d < BUCKET; d <<= 1) {
                unsigned y = __shfl_up(x, d, BUCKET);
                if (t >= d) x += y;
            }
            sstart[t] = x - c;
            scur[t] = x - c;
        }
        __syncthreads();

        // scatter into node-sorted LDS order
#pragma unroll
        for (int k = 0; k < 8; ++k) {
            if (r[k] != 0xFFFFFFFFu) {
                unsigned dl = r[k] >> 25;
                unsigned pos = atomicAdd(&scur[dl], 1u);
                sorted[pos] = r[k];
            }
        }
        __syncthreads();

        // register accumulation, 4 nodes per half-wave
        accum_run(support, sorted, aLds, sstart[hw * 4 + 0], scnt[hw * 4 + 0], lane, acc0);
        accum_run(support, sorted, aLds, sstart[hw * 4 + 1], scnt[hw * 4 + 1], lane, acc1);
        accum_run(support, sorted, aLds, sstart[hw * 4 + 2], scnt[hw * 4 + 2], lane, acc2);
        accum_run(support, sorted, aLds, sstart[hw * 4 + 3], scnt[hw * 4 + 3], lane, acc3);
    }

    // write out + bias, coalesced, single writer
    const int node0 = b * BUCKET + hw * 4;
#define WRITE_NODE(Q, ACC)                                                          \
    {                                                                               \
        int node = node0 + (Q);                                                     \
        if (node < N) {                                                             \
            float4 o = make_float4(ACC.x + b4.x, ACC.y + b4.y,                      \
                                   ACC.z + b4.z, ACC.w + b4.w);                     \
            *(float4*)&out[(size_t)node * 128 + lane * 4] = o;                      \
        }                                                                           \
    }
    WRITE_NODE(0, acc0)
    WRITE_NODE(1, acc1)
    WRITE_NODE(2, acc2)
    WRITE_NODE(3, acc3)
#undef WRITE_NODE
}

// ---------------------------------------------------------------------------
// Fallback path (constraints not met): VALU gemm + bias-init + atomic scatter
// ---------------------------------------------------------------------------
__global__ __launch_bounds__(256) void gemm_kernel(const float* __restrict__ A,
                                                   const float* __restrict__ W,
                                                   unsigned short* __restrict__ S,
                                                   int N) {
    __shared__ float sIn[128][33];
    __shared__ float sW[32][128];
    const int tid = threadIdx.x;
    const int tx = tid & 15;
    const int ty = tid >> 4;
    const int row0 = blockIdx.x * 128;
    float acc[8][8];
#pragma unroll
    for (int i = 0; i < 8; ++i)
#pragma unroll
        for (int j = 0; j < 8; ++j) acc[i][j] = 0.f;
    for (int kc = 0; kc < 128; kc += 32) {
#pragma unroll
        for (int p = 0; p < 4; ++p) {
            int r = p * 32 + (tid >> 3);
            int q = tid & 7;
            int grow = row0 + r;
            float4 v = make_float4(0.f, 0.f, 0.f, 0.f);
            if (grow < N) v = *(const float4*)&A[(size_t)grow * 128 + kc + q * 4];
            sIn[r][q * 4 + 0] = v.x; sIn[r][q * 4 + 1] = v.y;
            sIn[r][q * 4 + 2] = v.z; sIn[r][q * 4 + 3] = v.w;
        }
#pragma unroll
        for (int p = 0; p < 4; ++p) {
            int kr = p * 8 + (tid >> 5);
            int c4 = tid & 31;
            *(float4*)&sW[kr][c4 * 4] = *(const float4*)&W[(size_t)(kc + kr) * 128 + c4 * 4];
        }
        __syncthreads();
#pragma unroll
        for (int k = 0; k < 32; ++k) {
            float a[8];
#pragma unroll
            for (int i = 0; i < 8; ++i) a[i] = sIn[ty * 8 + i][k];
            float4 w0 = *(float4*)&sW[k][tx * 4];
            float4 w1 = *(float4*)&sW[k][64 + tx * 4];
#pragma unroll
            for (int i = 0; i < 8; ++i) {
                acc[i][0] += a[i] * w0.x; acc[i][1] += a[i] * w0.y;
                acc[i][2] += a[i] * w0.z; acc[i][3] += a[i] * w0.w;
                acc[i][4] += a[i] * w1.x; acc[i][5] += a[i] * w1.y;
                acc[i][6] += a[i] * w1.z; acc[i][7] += a[i] * w1.w;
            }
        }
        __syncthreads();
    }
#pragma unroll
    for (int i = 0; i < 8; ++i) {
        int grow = row0 + ty * 8 + i;
        if (grow < N) {
            unsigned short* Sp = S + (size_t)grow * 128;
            unsigned a0 = (unsigned)f2bf(acc[i][0]) | ((unsigned)f2bf(acc[i][1]) << 16);
            unsigned a1 = (unsigned)f2bf(acc[i][2]) | ((unsigned)f2bf(acc[i][3]) << 16);
            unsigned a2 = (unsigned)f2bf(acc[i][4]) | ((unsigned)f2bf(acc[i][5]) << 16);
            unsigned a3 = (unsigned)f2bf(acc[i][6]) | ((unsigned)f2bf(acc[i][7]) << 16);
            *(uint2*)&Sp[tx * 4] = make_uint2(a0, a1);
            *(uint2*)&Sp[64 + tx * 4] = make_uint2(a2, a3);
        }
    }
}

__global__ __launch_bounds__(256) void init_out_kernel(float* __restrict__ out,
                                                       const float* __restrict__ bias,
                                                       long long total4) {
    long long i = (long long)blockIdx.x * blockDim.x + threadIdx.x;
    if (i >= total4) return;
    float4 b = ((const float4*)bias)[(int)(i & 31)];
    ((float4*)out)[i] = b;
}

__global__ __launch_bounds__(256) void scatter_kernel(const unsigned short* __restrict__ support,
                                                      const int* __restrict__ ei,
                                                      const int* __restrict__ rel,
                                                      const float* __restrict__ alpha,
                                                      float* __restrict__ out,
                                                      int E) {
    long long tid = (long long)blockIdx.x * blockDim.x + threadIdx.x;
    long long mid = tid >> 5;
    if (mid >= 2LL * E) return;
    int lane4 = (int)(tid & 31);
    int dst = ei[mid];
    long long ms = (mid < E) ? mid + E : mid - E;
    int src = ei[ms];
    int e = (int)((mid < E) ? mid : mid - E);
    int rr = rel[e];
    float alp = (rr == 0) ? 0.f : alpha[rr];
    if (alp == 0.f) return;
    uint2 q = ((const uint2*)(support + (size_t)src * 128))[lane4];
    float* o = &out[(size_t)dst * 128 + lane4 * 4];
    atomicAdd(o + 0, alp * bfLo(q.x));
    atomicAdd(o + 1, alp * bfHi(q.x));
    atomicAdd(o + 2, alp * bfLo(q.y));
    atomicAdd(o + 3, alp * bfHi(q.y));
}

extern "C" void kernel_launch(void* const* d_in, const int* in_sizes, int n_in,
                              void* d_out, int out_size, void* d_ws, size_t ws_size,
                              hipStream_t stream) {
    const float* input  = (const float*)d_in[0];
    const int*   ei     = (const int*)d_in[1];    // int32 per harness contract
    const int*   rel    = (const int*)d_in[2];
    const float* weight = (const float*)d_in[4];
    const float* alpha  = (const float*)d_in[5];
    const float* bias   = (const float*)d_in[6];
    float*       out    = (float*)d_out;

    const int N = in_sizes[0] / 128;
    const int E = in_sizes[2];
    const int nAlpha = in_sizes[5];               // N_REL + 1
    const long long M = 2LL * E;
    const int nbuck = (N + BUCKET - 1) / BUCKET;

    // workspace layout
    char* ws = (char*)d_ws;
    size_t supB = ((size_t)N * 128 * 2 + 255) & ~(size_t)255;   // bf16 support
    const size_t curB = ((size_t)nbuck * 4 + 255) & ~(size_t)255;
    unsigned short* support = (unsigned short*)ws;
    unsigned* cursor = (unsigned*)(ws + supB);
    unsigned* rec    = (unsigned*)(ws + supB + curB);
    const size_t need = supB + curB + ((size_t)nbuck << CAP_SHIFT) * 4;

    const int gemmBlocks = (N + 127) / 128;
    const bool okMain = (ws_size >= need) && (N <= (1 << 17)) && (nAlpha <= 256) &&
                        (nbuck <= 4096) && ((long long)(M / (nbuck ? nbuck : 1)) * 2 <= (long long)CAP);

    if (okMain) {
        const long long chunk = ((long long)E + PART_BLOCKS - 1) / PART_BLOCKS;
        hipMemsetAsync(cursor, 0, (size_t)nbuck * 4, stream);
        partition_kernel<<<PART_BLOCKS, PART_TPB, 2 * nbuck * 4, stream>>>(
            ei, rel, cursor, rec, E, nbuck, chunk);
        mfma_gemm_kernel<<<gemmBlocks, 256, 0, stream>>>(input, weight, support, N);
        gather_bucket_kernel<<<nbuck, 256, 0, stream>>>(
            support, rec, cursor, alpha, bias, out, N, nAlpha);
    } else {
        gemm_kernel<<<gemmBlocks, 256, 0, stream>>>(input, weight, support, N);
        long long total4 = (long long)N * 32;
        init_out_kernel<<<(int)((total4 + 255) / 256), 256, 0, stream>>>(out, bias, total4);
        long long tthreads = M * 32;
        scatter_kernel<<<(int)((tthreads + 255) / 256), 256, 0, stream>>>(
            support, ei, rel, alpha, out, E);
    }
}